// Round 1
// baseline (2770.627 us; speedup 1.0000x reference)
//
#include <hip/hip_runtime.h>

// MinimalSSM: A_d = exp(A_log*dt) (diagonal), Bu = U@B^T, scan h=A_d*h+bu,
// Y = H@C^T + U@D^T. T=262144, D_IN=64, D_STATE=128.
// Round 0: exact chunked scan, fp32 vector math (no fp32 MFMA on CDNA4).
// K1: per-chunk local aggregate; K2: serial scan over 512 chunk aggregates;
// K3: recompute Bu per tile, apply carry, fused output GEMM.

#define TT    262144
#define DIN   64
#define DS    128
#define DTC   0.01f
#define LCH   512            // chunk length (timesteps per block)
#define NG    (TT / LCH)     // 512 chunks
#define TS    64             // tile timesteps inside a chunk
#define NTILE (LCH / TS)     // 8 tiles per chunk

// ---------------------------------------------------------------- K1
__global__ __launch_bounds__(512) void ssm_chunk_agg(
    const float* __restrict__ U, const float* __restrict__ Alog,
    const float* __restrict__ B, float* __restrict__ agg)
{
    __shared__ float sU[TS][DIN];    // 16 KB
    __shared__ float sBu[TS][DS];    // 32 KB
    const int g   = blockIdx.x;
    const int tid = threadIdx.x;
    const int s   = tid & (DS - 1);  // state id, 0..127
    const int p   = tid >> 7;        // row-group 0..3
    const float a = expf(Alog[s] * DTC);

    // B row for this state in registers (64 floats)
    float4 Brow[16];
    {
        const float4* B4 = (const float4*)(B + s * DIN);
        #pragma unroll
        for (int j = 0; j < 16; ++j) Brow[j] = B4[j];
    }

    float h = 0.0f;
    const float* Ub = U + (size_t)g * LCH * DIN;

    for (int tile = 0; tile < NTILE; ++tile) {
        // stage U tile: 64x64 fp32 = 1024 float4, 512 threads -> 2 each
        const float4* src = (const float4*)(Ub + tile * TS * DIN);
        float4* dst = (float4*)&sU[0][0];
        #pragma unroll
        for (int j = 0; j < 2; ++j) dst[tid + j * 512] = src[tid + j * 512];
        __syncthreads();

        // Bu[r][s] for r = p*16..p*16+15 (U rows broadcast across the wave)
        #pragma unroll
        for (int rr = 0; rr < 16; ++rr) {
            const int r = p * 16 + rr;
            const float4* u4 = (const float4*)&sU[r][0];
            float ax = 0.f, ay = 0.f, az = 0.f, aw = 0.f;
            #pragma unroll
            for (int j = 0; j < 16; ++j) {
                float4 uv = u4[j]; float4 bv = Brow[j];
                ax = fmaf(uv.x, bv.x, ax);
                ay = fmaf(uv.y, bv.y, ay);
                az = fmaf(uv.z, bv.z, az);
                aw = fmaf(uv.w, bv.w, aw);
            }
            sBu[r][s] = (ax + ay) + (az + aw);
        }
        __syncthreads();

        // sequential fold of this tile into the chunk aggregate
        if (tid < DS) {
            #pragma unroll
            for (int r = 0; r < TS; ++r) h = fmaf(a, h, sBu[r][s]);
        }
        __syncthreads();
    }
    if (tid < DS) agg[(size_t)g * DS + s] = h;
}

// ---------------------------------------------------------------- K2
__global__ void ssm_carry_scan(
    const float* __restrict__ Alog, const float* __restrict__ h0,
    const float* __restrict__ agg, float* __restrict__ carry,
    float* __restrict__ hfin)
{
    const int s = threadIdx.x;  // 128 threads, one per state
    const float aL = expf(Alog[s] * DTC * (float)LCH);
    float c = h0[s];
    for (int g = 0; g < NG; ++g) {
        carry[(size_t)g * DS + s] = c;
        c = fmaf(aL, c, agg[(size_t)g * DS + s]);
    }
    hfin[s] = c;
}

// ---------------------------------------------------------------- K3
__global__ __launch_bounds__(512) void ssm_chunk_out(
    const float* __restrict__ U, const float* __restrict__ Alog,
    const float* __restrict__ B, const float* __restrict__ C,
    const float* __restrict__ Dm, const float* __restrict__ carry,
    float* __restrict__ Y)
{
    __shared__ float sU[TS][DIN];        // 16 KB
    __shared__ float sBu[TS][DS];        // 32 KB (Bu, then H in place)
    __shared__ float sC[DIN][DS + 4];    // 33 KB, +4 pad: 16B-aligned rows, rotated banks
    __shared__ float sD[DIN][DIN + 4];   // 17 KB
    const int g   = blockIdx.x;
    const int tid = threadIdx.x;
    const int s   = tid & (DS - 1);
    const int p   = tid >> 7;            // 0..3  (Bu phase row group)
    const int i   = tid & (DIN - 1);     // output column in Y phase
    const int q   = tid >> 6;            // 0..7  (Y phase row group)
    const float a = expf(Alog[s] * DTC);

    float4 Brow[16];
    {
        const float4* B4 = (const float4*)(B + s * DIN);
        #pragma unroll
        for (int j = 0; j < 16; ++j) Brow[j] = B4[j];
    }

    for (int idx = tid; idx < DIN * DS; idx += 512)
        sC[idx >> 7][idx & (DS - 1)] = C[idx];
    for (int idx = tid; idx < DIN * DIN; idx += 512)
        sD[idx >> 6][idx & (DIN - 1)] = Dm[idx];

    float h = carry[(size_t)g * DS + s];   // valid where tid<128 (scan threads)

    const float* Ub = U + (size_t)g * LCH * DIN;
    float*       Yb = Y + (size_t)g * LCH * DIN;

    for (int tile = 0; tile < NTILE; ++tile) {
        const float4* src = (const float4*)(Ub + tile * TS * DIN);
        float4* dst = (float4*)&sU[0][0];
        #pragma unroll
        for (int j = 0; j < 2; ++j) dst[tid + j * 512] = src[tid + j * 512];
        __syncthreads();   // covers sC/sD staging on first tile too

        // Bu tile
        #pragma unroll
        for (int rr = 0; rr < 16; ++rr) {
            const int r = p * 16 + rr;
            const float4* u4 = (const float4*)&sU[r][0];
            float ax = 0.f, ay = 0.f, az = 0.f, aw = 0.f;
            #pragma unroll
            for (int j = 0; j < 16; ++j) {
                float4 uv = u4[j]; float4 bv = Brow[j];
                ax = fmaf(uv.x, bv.x, ax);
                ay = fmaf(uv.y, bv.y, ay);
                az = fmaf(uv.z, bv.z, az);
                aw = fmaf(uv.w, bv.w, aw);
            }
            sBu[r][s] = (ax + ay) + (az + aw);
        }
        __syncthreads();

        // sequential scan over the tile, H written in place over Bu
        if (tid < DS) {
            #pragma unroll
            for (int r = 0; r < TS; ++r) {
                h = fmaf(a, h, sBu[r][s]);
                sBu[r][s] = h;
            }
        }
        __syncthreads();

        // Y tile: Y[r][i] = H[r,:]·C[i,:] + U[r,:]·D[i,:]
        #pragma unroll
        for (int rr = 0; rr < 8; ++rr) {
            const int r = q * 8 + rr;
            float ax = 0.f, ay = 0.f, az = 0.f, aw = 0.f;
            const float4* h4 = (const float4*)&sBu[r][0];   // broadcast
            const float4* c4 = (const float4*)&sC[i][0];    // rotated banks
            #pragma unroll
            for (int j = 0; j < DS / 4; ++j) {
                float4 hv = h4[j]; float4 cv = c4[j];
                ax = fmaf(hv.x, cv.x, ax);
                ay = fmaf(hv.y, cv.y, ay);
                az = fmaf(hv.z, cv.z, az);
                aw = fmaf(hv.w, cv.w, aw);
            }
            const float4* u4 = (const float4*)&sU[r][0];    // broadcast
            const float4* d4 = (const float4*)&sD[i][0];
            #pragma unroll
            for (int j = 0; j < DIN / 4; ++j) {
                float4 uv = u4[j]; float4 dv = d4[j];
                ax = fmaf(uv.x, dv.x, ax);
                ay = fmaf(uv.y, dv.y, ay);
                az = fmaf(uv.z, dv.z, az);
                aw = fmaf(uv.w, dv.w, aw);
            }
            Yb[(tile * TS + r) * DIN + i] = (ax + ay) + (az + aw);
        }
        __syncthreads();
    }
}

// ---------------------------------------------------------------- launch
extern "C" void kernel_launch(void* const* d_in, const int* in_sizes, int n_in,
                              void* d_out, int out_size, void* d_ws, size_t ws_size,
                              hipStream_t stream)
{
    const float* U    = (const float*)d_in[0];
    const float* Alog = (const float*)d_in[1];
    const float* B    = (const float*)d_in[2];
    const float* C    = (const float*)d_in[3];
    const float* Dm   = (const float*)d_in[4];
    const float* h0   = (const float*)d_in[5];

    float* out  = (float*)d_out;
    float* Yp   = out;                        // T*DIN
    float* hfin = out + (size_t)TT * DIN;     // 128

    // workspace: agg (NG*DS) + carry (NG*DS) = 512 KB
    float* agg   = (float*)d_ws;
    float* carry = agg + (size_t)NG * DS;

    ssm_chunk_agg<<<NG, 512, 0, stream>>>(U, Alog, B, agg);
    ssm_carry_scan<<<1, DS, 0, stream>>>(Alog, h0, agg, carry, hfin);
    ssm_chunk_out<<<NG, 512, 0, stream>>>(U, Alog, B, C, Dm, carry, Yp);
}

// Round 2
// 210.805 us; speedup vs baseline: 13.1431x; 13.1431x over previous
//
#include <hip/hip_runtime.h>

// MinimalSSM on MFMA (bf16): Bu = U@B^T, diagonal scan (fp32, exact chunked),
// Y = H@C^T + U@D^T.  T=262144, DIN=64, DS=128.
// Chunk L=128 -> 2048 blocks. 16x16x32 bf16 MFMA; C/D layout col=lane&15,
// row=(lane>>4)*4+reg; A layout A[m=lane&15][k=(lane>>4)*8+j] (m89/m120).
// A-fragments staged in LDS in fragment order with XOR swizzle (bank-clean
// ds_read_b128). B/C/D operand fragments loaded to registers from global.

#define TT   262144
#define DIN  64
#define DS   128
#define DTC  0.01f
#define L    128
#define NG   (TT / L)        // 2048 chunks
#define SEGL 32              // chunks per segment
#define NSEG (NG / SEGL)     // 64 segments

typedef short  s8v  __attribute__((ext_vector_type(8)));
typedef float  f4v  __attribute__((ext_vector_type(4)));

__device__ __forceinline__ unsigned short f2bf(float f) {
    unsigned u = __float_as_uint(f);
    u += 0x7fffu + ((u >> 16) & 1u);        // round-to-nearest-even
    return (unsigned short)(u >> 16);
}

__device__ __forceinline__ s8v pack8(float4 a, float4 b) {
    union { unsigned short u[8]; s8v v; } r;
    r.u[0] = f2bf(a.x); r.u[1] = f2bf(a.y); r.u[2] = f2bf(a.z); r.u[3] = f2bf(a.w);
    r.u[4] = f2bf(b.x); r.u[5] = f2bf(b.y); r.u[6] = f2bf(b.z); r.u[7] = f2bf(b.w);
    return r.v;
}

// XOR swizzle of the lane field of an A-frag slot (bank-rotates quads)
__device__ __forceinline__ int swl(int lane) {
    int q = lane >> 4, m = lane & 15;
    return (q << 4) | (m ^ (q << 2));
}

// B-operand fragment from a row-major matrix M (ld floats): lane holds
// Bop[k=k0..k0+7][n=row]; = M[row][k0..k0+7] for the B^T-style GEMMs here.
__device__ __forceinline__ s8v load_bfrag(const float* __restrict__ M,
                                          int row, int k0, int ld) {
    const float4* p = (const float4*)(M + row * ld + k0);
    return pack8(p[0], p[1]);
}

// Stage one chunk of U (L x 64 fp32) into LDS as bf16 A-fragments.
// slot(mt,ks,lane) = (mt*2+ks)*64 + swl(lane); frag elem j <-> k=ks*32+q*8+j.
__device__ __forceinline__ void stage_U(const float* __restrict__ Ug,
                                        unsigned short* __restrict__ sA,
                                        int tid) {
    #pragma unroll
    for (int u = tid; u < (L / 16) * 8 * 16; u += 512) {   // 1024 units
        int t = u >> 3, oct = u & 7;                        // oct = k/8
        const float4* gp = (const float4*)(Ug + t * 64 + oct * 8);
        float4 x = gp[0], y = gp[1];
        int mt = t >> 4, ks = oct >> 2, q = oct & 3, m = t & 15;
        int slot = (mt * 2 + ks) * 64 + ((q << 4) | (m ^ (q << 2)));
        *(s8v*)&sA[slot * 8] = pack8(x, y);
    }
}

// ---------------------------------------------------------------- K1
// Per-chunk aggregate agg[g][s] = sum_t a^(L-1-t) Bu[t,s]; also fold the
// weighted contribution into segAgg via device atomics.
__global__ __launch_bounds__(512) void ssm_k1(
    const float* __restrict__ U, const float* __restrict__ Alog,
    const float* __restrict__ B, float* __restrict__ agg,
    float* __restrict__ segAgg)
{
    __shared__ __align__(16) unsigned short sA[8 * 2 * 64 * 8];  // 16 KB
    __shared__ __align__(16) float sBu[64 * 132];                // 33 KB
    const int g    = blockIdx.x;
    const int tid  = threadIdx.x;
    const int lane = tid & 63;
    const int w    = tid >> 6;          // wave 0..7 = state strip
    const int q    = lane >> 4, m = lane & 15;

    stage_U(U + (size_t)g * L * DIN, sA, tid);

    s8v Bf[2];
    #pragma unroll
    for (int ks = 0; ks < 2; ++ks)
        Bf[ks] = load_bfrag(B, 16 * w + m, ks * 32 + q * 8, DIN);

    float a_s = 0.f, hreg = 0.f;
    if (tid < DS) a_s = __expf(Alog[tid] * DTC);
    __syncthreads();

    #pragma unroll
    for (int hh = 0; hh < 2; ++hh) {
        f4v acc[4];
        #pragma unroll
        for (int mtl = 0; mtl < 4; ++mtl) {
            acc[mtl] = (f4v){0.f, 0.f, 0.f, 0.f};
            const int mt = hh * 4 + mtl;
            #pragma unroll
            for (int ks = 0; ks < 2; ++ks) {
                s8v af = *(const s8v*)&sA[((mt * 2 + ks) * 64 + swl(lane)) * 8];
                acc[mtl] = __builtin_amdgcn_mfma_f32_16x16x32_bf16(af, Bf[ks], acc[mtl], 0, 0, 0);
            }
        }
        #pragma unroll
        for (int mtl = 0; mtl < 4; ++mtl)
            #pragma unroll
            for (int r = 0; r < 4; ++r)
                sBu[(mtl * 16 + q * 4 + r) * 132 + 16 * w + m] = acc[mtl][r];
        __syncthreads();

        if (tid < DS) {
            #pragma unroll
            for (int r = 0; r < 64; ++r)
                hreg = fmaf(a_s, hreg, sBu[r * 132 + tid]);
        }
        __syncthreads();
    }

    if (tid < DS) {
        agg[(size_t)g * DS + tid] = hreg;
        float wgt = __expf(Alog[tid] * (DTC * L) * (float)(SEGL - 1 - (g & (SEGL - 1))));
        atomicAdd(&segAgg[(g >> 5) * DS + tid], hreg * wgt);
    }
}

// ---------------------------------------------------------------- K2
// Serial scan over 64 segment aggregates -> segment carries + h_final.
__global__ void ssm_k2(const float* __restrict__ Alog, const float* __restrict__ h0,
                       const float* __restrict__ segAgg, float* __restrict__ segCarry,
                       float* __restrict__ hfin)
{
    const int s = threadIdx.x;                         // 128 threads
    const float aSeg = __expf(Alog[s] * (DTC * L * SEGL));   // a^(L*SEGL)
    float c = h0[s];
    #pragma unroll 4
    for (int sg = 0; sg < NSEG; ++sg) {
        segCarry[sg * DS + s] = c;
        c = fmaf(aSeg, c, segAgg[sg * DS + s]);
    }
    hfin[s] = c;
}

// ---------------------------------------------------------------- K3
// Re-derive chunk carry from segCarry + L2-hot agg, recompute Bu via MFMA,
// scan in LDS, pack H to bf16 A-frags, fused Y = H@C^T + U@D^T via MFMA.
__global__ __launch_bounds__(512) void ssm_k3(
    const float* __restrict__ U, const float* __restrict__ Alog,
    const float* __restrict__ B, const float* __restrict__ C,
    const float* __restrict__ Dm, const float* __restrict__ agg,
    const float* __restrict__ segCarry, float* __restrict__ Y)
{
    __shared__ __align__(16) unsigned short sA[8 * 2 * 64 * 8];  // 16 KB
    __shared__ __align__(16) float sBu[64 * 132];                // 33 KB
    __shared__ __align__(16) unsigned short sH[4 * 4 * 64 * 8];  // 16 KB
    const int g    = blockIdx.x;
    const int tid  = threadIdx.x;
    const int lane = tid & 63;
    const int w    = tid >> 6;
    const int q    = lane >> 4, m = lane & 15;

    stage_U(U + (size_t)g * L * DIN, sA, tid);

    s8v Bf[2], Cf[4], Df[2];
    #pragma unroll
    for (int ks = 0; ks < 2; ++ks)
        Bf[ks] = load_bfrag(B, 16 * w + m, ks * 32 + q * 8, DIN);
    const int iC = 16 * (w & 3) + m;
    #pragma unroll
    for (int ks = 0; ks < 4; ++ks)
        Cf[ks] = load_bfrag(C, iC, ks * 32 + q * 8, DS);
    #pragma unroll
    for (int ks = 0; ks < 2; ++ks)
        Df[ks] = load_bfrag(Dm, iC, ks * 32 + q * 8, DIN);

    // carry into this chunk: segment carry + in-order fold of preceding chunks
    float a_s = 0.f, hreg = 0.f;
    if (tid < DS) {
        a_s = __expf(Alog[tid] * DTC);
        const float aL = __expf(Alog[tid] * (DTC * L));
        float c0 = segCarry[(g >> 5) * DS + tid];
        for (int c = g & ~(SEGL - 1); c < g; ++c)
            c0 = fmaf(aL, c0, agg[(size_t)c * DS + tid]);
        hreg = c0;
    }
    __syncthreads();

    #pragma unroll
    for (int hh = 0; hh < 2; ++hh) {
        // ---- GEMM1: Bu tile (64 t x 128 s), wave = 16-state strip
        f4v acc[4];
        #pragma unroll
        for (int mtl = 0; mtl < 4; ++mtl) {
            acc[mtl] = (f4v){0.f, 0.f, 0.f, 0.f};
            const int mt = hh * 4 + mtl;
            #pragma unroll
            for (int ks = 0; ks < 2; ++ks) {
                s8v af = *(const s8v*)&sA[((mt * 2 + ks) * 64 + swl(lane)) * 8];
                acc[mtl] = __builtin_amdgcn_mfma_f32_16x16x32_bf16(af, Bf[ks], acc[mtl], 0, 0, 0);
            }
        }
        #pragma unroll
        for (int mtl = 0; mtl < 4; ++mtl)
            #pragma unroll
            for (int r = 0; r < 4; ++r)
                sBu[(mtl * 16 + q * 4 + r) * 132 + 16 * w + m] = acc[mtl][r];
        __syncthreads();

        // ---- exact fp32 scan over 64 timesteps, H written in place
        if (tid < DS) {
            #pragma unroll
            for (int r = 0; r < 64; ++r) {
                hreg = fmaf(a_s, hreg, sBu[r * 132 + tid]);
                sBu[r * 132 + tid] = hreg;
            }
        }
        __syncthreads();

        // ---- pack H -> bf16 A-fragments
        #pragma unroll
        for (int u = tid; u < 1024; u += 512) {
            int lp = u & 63, ks4 = (u >> 6) & 3, mth = (u >> 8) & 3;
            int qq = (lp >> 4) & 3, mm = lp & 15;
            int t = mth * 16 + mm, s0 = ks4 * 32 + qq * 8;
            const float4* hp = (const float4*)&sBu[t * 132 + s0];
            int slot = (mth * 4 + ks4) * 64 + ((qq << 4) | (mm ^ (qq << 2)));
            *(s8v*)&sH[slot * 8] = pack8(hp[0], hp[1]);
        }
        __syncthreads();

        // ---- GEMM2: Y tile (64 t x 64 i) = H@C^T + U@D^T
        const int mm2 = w >> 2;                  // t-tile pair
        #pragma unroll
        for (int ti = 0; ti < 2; ++ti) {
            const int mtl = mm2 * 2 + ti;
            f4v acc2 = (f4v){0.f, 0.f, 0.f, 0.f};
            #pragma unroll
            for (int ks = 0; ks < 4; ++ks) {
                s8v ah = *(const s8v*)&sH[((mtl * 4 + ks) * 64 + swl(lane)) * 8];
                acc2 = __builtin_amdgcn_mfma_f32_16x16x32_bf16(ah, Cf[ks], acc2, 0, 0, 0);
            }
            #pragma unroll
            for (int ks = 0; ks < 2; ++ks) {
                s8v au = *(const s8v*)&sA[(((hh * 4 + mtl) * 2 + ks) * 64 + swl(lane)) * 8];
                acc2 = __builtin_amdgcn_mfma_f32_16x16x32_bf16(au, Df[ks], acc2, 0, 0, 0);
            }
            const size_t tb = (size_t)g * L + hh * 64 + mtl * 16 + q * 4;
            #pragma unroll
            for (int r = 0; r < 4; ++r)
                Y[(tb + r) * DIN + iC] = acc2[r];
        }
        __syncthreads();   // protect sBu/sH for next half
    }
}

// ---------------------------------------------------------------- launch
extern "C" void kernel_launch(void* const* d_in, const int* in_sizes, int n_in,
                              void* d_out, int out_size, void* d_ws, size_t ws_size,
                              hipStream_t stream)
{
    const float* U    = (const float*)d_in[0];
    const float* Alog = (const float*)d_in[1];
    const float* B    = (const float*)d_in[2];
    const float* C    = (const float*)d_in[3];
    const float* Dm   = (const float*)d_in[4];
    const float* h0   = (const float*)d_in[5];

    float* out  = (float*)d_out;
    float* Yp   = out;                        // T*DIN
    float* hfin = out + (size_t)TT * DIN;     // 128

    float* agg      = (float*)d_ws;                 // NG*DS      (1 MB)
    float* segAgg   = agg + (size_t)NG * DS;        // NSEG*DS    (32 KB)
    float* segCarry = segAgg + (size_t)NSEG * DS;   // NSEG*DS    (32 KB)

    hipMemsetAsync(segAgg, 0, (size_t)NSEG * DS * sizeof(float), stream);
    ssm_k1<<<NG, 512, 0, stream>>>(U, Alog, B, agg, segAgg);
    ssm_k2<<<1, DS, 0, stream>>>(Alog, h0, segAgg, segCarry, hfin);
    ssm_k3<<<NG, 512, 0, stream>>>(U, Alog, B, C, Dm, agg, segCarry, Yp);
}